// Round 2
// baseline (207.993 us; speedup 1.0000x reference)
//
#include <hip/hip_runtime.h>

// CrossAttention restructured:  out = x @ ((K^T Q) @ W^T) + b
//   K = softmax(x2, axis=-1) (over D), Q = softmax(x2, axis=1) (over N)
// 19.3 GFLOP instead of the reference's 77 GFLOP; no [N,N] intermediate.

typedef __attribute__((ext_vector_type(8))) short          s16x8;
typedef __attribute__((ext_vector_type(8))) unsigned short u16x8;
typedef __attribute__((ext_vector_type(4))) float          f32x4;

#define B_ 8
#define N_ 2048
#define D_ 512

__device__ inline unsigned short f2bf(float f) {  // f32 -> bf16 RNE
    unsigned u = __float_as_uint(f);
    u += 0x7FFFu + ((u >> 16) & 1u);
    return (unsigned short)(u >> 16);
}

// ---------- row sums of exp over D (key softmax denom); stores reciprocal ----------
__global__ __launch_bounds__(256) void rowsum_exp_k(const float* __restrict__ x2,
                                                    float* __restrict__ rks) {
    int w = threadIdx.x >> 6, l = threadIdx.x & 63;
    int r = blockIdx.x * 4 + w;                       // [0, B*N)
    const float* p = x2 + (size_t)r * D_ + l * 8;
    float4 a = *(const float4*)p;
    float4 b = *(const float4*)(p + 4);
    float s = __expf(a.x) + __expf(a.y) + __expf(a.z) + __expf(a.w)
            + __expf(b.x) + __expf(b.y) + __expf(b.z) + __expf(b.w);
#pragma unroll
    for (int off = 1; off < 64; off <<= 1) s += __shfl_xor(s, off);
    if (l == 0) rks[r] = 1.0f / s;
}

// ---------- column sums of exp over N (query softmax denom), partial + atomic ----------
__global__ __launch_bounds__(512) void colsum_exp_k(const float* __restrict__ x2,
                                                    float* __restrict__ qs) {
    int d = threadIdx.x;                              // 512 columns
    int b = blockIdx.y, mc = blockIdx.x;              // 16 chunks of 128 rows
    const float* p = x2 + ((size_t)b * N_ + (size_t)mc * 128) * D_ + d;
    float s = 0.f;
#pragma unroll 4
    for (int mm = 0; mm < 128; ++mm) s += __expf(p[(size_t)mm * D_]);
    atomicAdd(&qs[b * D_ + d], s);
}

// ---------- fused softmax + transpose: Kt[b][d][m], Qt[b][d][m] (bf16) ----------
__global__ __launch_bounds__(256) void softmax_tr_k(const float* __restrict__ x2,
                                                    const float* __restrict__ rks,
                                                    const float* __restrict__ qs,
                                                    unsigned short* __restrict__ Kt,
                                                    unsigned short* __restrict__ Qt) {
    __shared__ unsigned short kt[64][65], qt[64][65];   // +1 pad: write conflicts ~2-way
    int b = blockIdx.z, d0 = blockIdx.y * 64, m0 = blockIdx.x * 64;
    int tx = threadIdx.x & 63, w = threadIdx.x >> 6;
    float rq = 1.0f / qs[b * D_ + d0 + tx];
#pragma unroll
    for (int it = 0; it < 16; ++it) {
        int row = w * 16 + it;                          // wave-uniform row
        float v = x2[((size_t)b * N_ + m0 + row) * D_ + d0 + tx];
        float e = __expf(v);
        float rk = rks[b * N_ + m0 + row];              // uniform -> scalar load
        kt[tx][row] = f2bf(e * rk);
        qt[tx][row] = f2bf(e * rq);
    }
    __syncthreads();
#pragma unroll
    for (int it = 0; it < 16; ++it) {
        int dr = w * 16 + it;
        size_t off = ((size_t)b * D_ + d0 + dr) * N_ + m0 + tx;
        Kt[off] = kt[dr][tx];
        Qt[off] = qt[dr][tx];
    }
}

// ---------- f32 -> bf16 bulk convert, 8 elems/thread ----------
__global__ __launch_bounds__(256) void cvt_bf16_k(const float* __restrict__ in,
                                                  unsigned short* __restrict__ out) {
    size_t i = ((size_t)blockIdx.x * 256 + threadIdx.x) * 8;
    float4 a = *(const float4*)(in + i);
    float4 b = *(const float4*)(in + i + 4);
    u16x8 o;
    o[0] = f2bf(a.x); o[1] = f2bf(a.y); o[2] = f2bf(a.z); o[3] = f2bf(a.w);
    o[4] = f2bf(b.x); o[5] = f2bf(b.y); o[6] = f2bf(b.z); o[7] = f2bf(b.w);
    *(u16x8*)(out + i) = o;
}

// ---------- batched MFMA GEMM: C[M,N] = A[M,K] * B[N,K]^T (both k-contiguous) ----------
__device__ inline void gload16(const unsigned short* g, unsigned short* l) {
    __builtin_amdgcn_global_load_lds((const __attribute__((address_space(1))) void*)g,
                                     (__attribute__((address_space(3))) void*)l, 16, 0, 0);
}

template <bool OUT_BF16, bool BIAS>
__global__ __launch_bounds__(256, 2) void gemm_bt_k(const unsigned short* __restrict__ A,
                                                    const unsigned short* __restrict__ Bm,
                                                    void* __restrict__ Cv,
                                                    const float* __restrict__ bias,
                                                    int M, int N, int K,
                                                    long long sA, long long sB, long long sC) {
    __shared__ unsigned short As[128 * 32], Bs[128 * 32];   // 8 KB each
    int b = blockIdx.z;
    const unsigned short* Ab = A + (size_t)b * sA;
    const unsigned short* Bb = Bm + (size_t)b * sB;
    int tm = blockIdx.y, tn = blockIdx.x;
    int tid = threadIdx.x, w = tid >> 6, l = tid & 63;
    int wr = w >> 1, wc = w & 1;                 // 2x2 waves, each owns 64x64
    int lr = l & 15, lg = l >> 4;

    f32x4 acc[4][4];
#pragma unroll
    for (int i = 0; i < 4; ++i)
#pragma unroll
        for (int j = 0; j < 4; ++j) acc[i][j] = (f32x4){0.f, 0.f, 0.f, 0.f};

    const int rowbase = tm * 128, colbase = tn * 128;

    for (int kt = 0; kt < K; kt += 32) {
        // stage 128x32 bf16 tiles via global_load_lds (16B/lane, linear LDS dest)
#pragma unroll
        for (int i = 0; i < 2; ++i) {
            int ci = (i * 4 + w) * 64 + l;       // chunk index in [0,512)
            int row = ci >> 2, cc = ci & 3;      // 4 x 16B chunks per 64B row
            gload16(Ab + (size_t)(rowbase + row) * K + kt + cc * 8, As + (i * 4 + w) * 512);
            gload16(Bb + (size_t)(colbase + row) * K + kt + cc * 8, Bs + (i * 4 + w) * 512);
        }
        __syncthreads();                          // drains vmcnt -> LDS tiles ready
        s16x8 af[4], bf[4];
#pragma unroll
        for (int i = 0; i < 4; ++i)
            af[i] = *(const s16x8*)&As[(wr * 64 + i * 16 + lr) * 32 + lg * 8];
#pragma unroll
        for (int j = 0; j < 4; ++j)
            bf[j] = *(const s16x8*)&Bs[(wc * 64 + j * 16 + lr) * 32 + lg * 8];
#pragma unroll
        for (int i = 0; i < 4; ++i)
#pragma unroll
            for (int j = 0; j < 4; ++j)
                acc[i][j] = __builtin_amdgcn_mfma_f32_16x16x32_bf16(af[i], bf[j], acc[i][j], 0, 0, 0);
        __syncthreads();                          // protect LDS before next stage
    }

    // epilogue: C/D layout col=lane&15, row=(lane>>4)*4+reg (m89-verified)
    if (OUT_BF16) {
        unsigned short* C = (unsigned short*)Cv + (size_t)b * sC;
#pragma unroll
        for (int i = 0; i < 4; ++i)
#pragma unroll
            for (int j = 0; j < 4; ++j) {
                int col = colbase + wc * 64 + j * 16 + lr;
#pragma unroll
                for (int r = 0; r < 4; ++r) {
                    int row = rowbase + wr * 64 + i * 16 + lg * 4 + r;
                    C[(size_t)row * N + col] = f2bf(acc[i][j][r]);
                }
            }
    } else {
        float* C = (float*)Cv + (size_t)b * sC;
#pragma unroll
        for (int i = 0; i < 4; ++i)
#pragma unroll
            for (int j = 0; j < 4; ++j) {
                int col = colbase + wc * 64 + j * 16 + lr;
                float bv = BIAS ? bias[col] : 0.f;
#pragma unroll
                for (int r = 0; r < 4; ++r) {
                    int row = rowbase + wr * 64 + i * 16 + lg * 4 + r;
                    C[(size_t)row * N + col] = acc[i][j][r] + bv;
                }
            }
    }
}

extern "C" void kernel_launch(void* const* d_in, const int* in_sizes, int n_in,
                              void* d_out, int out_size, void* d_ws, size_t ws_size,
                              hipStream_t stream) {
    const float* x    = (const float*)d_in[0];   // [8,2048,512]
    const float* x2   = (const float*)d_in[1];   // [8,2048,512]
    const float* W    = (const float*)d_in[2];   // [512,512]
    const float* bias = (const float*)d_in[3];   // [512]
    float* out = (float*)d_out;                  // [8,2048,512] f32

    // workspace carve (bf16 stored as ushort) — ~57 MB total
    unsigned short* Kt = (unsigned short*)d_ws;          // [8][512][2048]
    unsigned short* Qt = Kt + 8388608;                   // [8][512][2048]
    unsigned short* xb = Qt + 8388608;                   // [8][2048][512]
    unsigned short* Wb = xb + 8388608;                   // [512][512]
    unsigned short* KQ = Wb + 262144;                    // [8][512][512]
    unsigned short* Mt = KQ + 2097152;                   // [8][512][512]
    float* rks = (float*)(Mt + 2097152);                 // [8*2048]
    float* qs  = rks + 16384;                            // [8*512]

    hipMemsetAsync(qs, 0, (size_t)B_ * D_ * sizeof(float), stream);

    // softmax denominators
    rowsum_exp_k<<<dim3(B_ * N_ / 4), 256, 0, stream>>>(x2, rks);
    colsum_exp_k<<<dim3(16, B_), 512, 0, stream>>>(x2, qs);

    // softmax + transpose -> Kt, Qt (bf16, [d][m])
    softmax_tr_k<<<dim3(N_ / 64, D_ / 64, B_), 256, 0, stream>>>(x2, rks, qs, Kt, Qt);

    // bf16 copies of x and W
    cvt_bf16_k<<<dim3(4096), 256, 0, stream>>>(x, xb);
    cvt_bf16_k<<<dim3(128), 256, 0, stream>>>(W, Wb);

    // pass 2: KQ[i][j] = sum_m Kt[i][m] * Qt[j][m]      (M=512,N=512,K=2048)
    gemm_bt_k<true, false><<<dim3(4, 4, B_), 256, 0, stream>>>(
        Kt, Qt, KQ, nullptr, 512, 512, 2048,
        (long long)512 * 2048, (long long)512 * 2048, (long long)512 * 512);

    // pass 3: Mt[e][i] = sum_j W[e][j] * KQ[i][j]       (M=512,N=512,K=512)
    gemm_bt_k<true, false><<<dim3(4, 4, B_), 256, 0, stream>>>(
        Wb, KQ, Mt, nullptr, 512, 512, 512,
        0LL, (long long)512 * 512, (long long)512 * 512);

    // pass 4: out[n][e] = sum_i xb[n][i] * Mt[e][i] + b[e]  (M=2048,N=512,K=512)
    gemm_bt_k<false, true><<<dim3(4, 16, B_), 256, 0, stream>>>(
        xb, Mt, out, bias, 2048, 512, 512,
        (long long)2048 * 512, (long long)512 * 512, (long long)2048 * 512);
}

// Round 3
// 193.478 us; speedup vs baseline: 1.0750x; 1.0750x over previous
//
#include <hip/hip_runtime.h>

// CrossAttention restructured:  out = x @ ((K^T Q) @ W^T) + b
//   K = softmax(x2, axis=-1) (over D), Q = softmax(x2, axis=1) (over N)
// R2: pass2/3 re-parallelized (64^2 tiles, split-K atomics), fused denom sums.

typedef __attribute__((ext_vector_type(8))) short          s16x8;
typedef __attribute__((ext_vector_type(8))) unsigned short u16x8;
typedef __attribute__((ext_vector_type(4))) float          f32x4;

#define B_ 8
#define N_ 2048
#define D_ 512

__device__ inline unsigned short f2bf(float f) {  // f32 -> bf16 RNE
    unsigned u = __float_as_uint(f);
    u += 0x7FFFu + ((u >> 16) & 1u);
    return (unsigned short)(u >> 16);
}

// ---------- fused softmax denominators: one x2 read -> rks (recip row sums), qs (col sums) ----------
__global__ __launch_bounds__(256) void fused_sums_k(const float* __restrict__ x2,
                                                    float* __restrict__ rks,
                                                    float* __restrict__ qs) {
    __shared__ float cp[4][512];                      // per-wave column partials, 8 KB
    int w = threadIdx.x >> 6, l = threadIdx.x & 63;
    int rbase = blockIdx.x * 32;                      // 32 rows/block, same batch (32|2048)
    int b = rbase / N_;
    const int c0 = l * 8;
    float colacc[8] = {0.f, 0.f, 0.f, 0.f, 0.f, 0.f, 0.f, 0.f};
#pragma unroll
    for (int rr = 0; rr < 8; ++rr) {
        int r = rbase + w * 8 + rr;
        const float* p = x2 + (size_t)r * D_ + c0;
        float4 a = *(const float4*)p;
        float4 bb = *(const float4*)(p + 4);
        float e0 = __expf(a.x), e1 = __expf(a.y), e2 = __expf(a.z), e3 = __expf(a.w);
        float e4 = __expf(bb.x), e5 = __expf(bb.y), e6 = __expf(bb.z), e7 = __expf(bb.w);
        float s = e0 + e1 + e2 + e3 + e4 + e5 + e6 + e7;
#pragma unroll
        for (int off = 1; off < 64; off <<= 1) s += __shfl_xor(s, off);
        if (l == 0) rks[r] = 1.0f / s;
        colacc[0] += e0; colacc[1] += e1; colacc[2] += e2; colacc[3] += e3;
        colacc[4] += e4; colacc[5] += e5; colacc[6] += e6; colacc[7] += e7;
    }
#pragma unroll
    for (int c = 0; c < 8; ++c) cp[w][c0 + c] = colacc[c];
    __syncthreads();
    for (int c = threadIdx.x; c < 512; c += 256) {
        float s = cp[0][c] + cp[1][c] + cp[2][c] + cp[3][c];
        atomicAdd(&qs[b * D_ + c], s);
    }
}

// ---------- fused softmax + transpose: Kt[b][d][m], Qt[b][d][m] (bf16) ----------
__global__ __launch_bounds__(256) void softmax_tr_k(const float* __restrict__ x2,
                                                    const float* __restrict__ rks,
                                                    const float* __restrict__ qs,
                                                    unsigned short* __restrict__ Kt,
                                                    unsigned short* __restrict__ Qt) {
    __shared__ unsigned short kt[64][65], qt[64][65];
    int b = blockIdx.z, d0 = blockIdx.y * 64, m0 = blockIdx.x * 64;
    int tx = threadIdx.x & 63, w = threadIdx.x >> 6;
    float rq = 1.0f / qs[b * D_ + d0 + tx];
#pragma unroll
    for (int it = 0; it < 16; ++it) {
        int row = w * 16 + it;
        float v = x2[((size_t)b * N_ + m0 + row) * D_ + d0 + tx];
        float e = __expf(v);
        float rk = rks[b * N_ + m0 + row];
        kt[tx][row] = f2bf(e * rk);
        qt[tx][row] = f2bf(e * rq);
    }
    __syncthreads();
#pragma unroll
    for (int it = 0; it < 16; ++it) {
        int dr = w * 16 + it;
        size_t off = ((size_t)b * D_ + d0 + dr) * N_ + m0 + tx;
        Kt[off] = kt[dr][tx];
        Qt[off] = qt[dr][tx];
    }
}

// ---------- f32 -> bf16 bulk convert, 8 elems/thread ----------
__global__ __launch_bounds__(256) void cvt_bf16_k(const float* __restrict__ in,
                                                  unsigned short* __restrict__ out) {
    size_t i = ((size_t)blockIdx.x * 256 + threadIdx.x) * 8;
    float4 a = *(const float4*)(in + i);
    float4 b = *(const float4*)(in + i + 4);
    u16x8 o;
    o[0] = f2bf(a.x); o[1] = f2bf(a.y); o[2] = f2bf(a.z); o[3] = f2bf(a.w);
    o[4] = f2bf(b.x); o[5] = f2bf(b.y); o[6] = f2bf(b.z); o[7] = f2bf(b.w);
    *(u16x8*)(out + i) = o;
}

__device__ inline void gload16(const unsigned short* g, unsigned short* l) {
    __builtin_amdgcn_global_load_lds((const __attribute__((address_space(1))) void*)g,
                                     (__attribute__((address_space(3))) void*)l, 16, 0, 0);
}

// ---------- 64x64-tile MFMA GEMM, optional split-K. C = A[M,K] * B[N,K]^T ----------
// MODE 0: atomicAdd into f32 C (split-K partials).  MODE 2: direct bf16 store.
template <int MODE>
__global__ __launch_bounds__(256, 4) void gemm64_k(const unsigned short* __restrict__ A,
                                                   const unsigned short* __restrict__ Bm,
                                                   void* __restrict__ Cv,
                                                   int M, int N, int K, int nsplit,
                                                   long long sA, long long sB, long long sC) {
    __shared__ unsigned short As[64 * 32], Bs[64 * 32];   // 4 KB each
    int b = blockIdx.z / nsplit, ks = blockIdx.z % nsplit;
    int klen = K / nsplit, k0 = ks * klen;
    const unsigned short* Ab = A + (size_t)b * sA;
    const unsigned short* Bb = Bm + (size_t)b * sB;
    int tid = threadIdx.x, w = tid >> 6, l = tid & 63;
    int wr = w >> 1, wc = w & 1;                 // 2x2 waves, each owns 32x32
    int lr = l & 15, lg = l >> 4;
    int srow = tid >> 2, scc = tid & 3;          // staging: 1 x 16B chunk / thread / tile

    f32x4 acc[2][2];
#pragma unroll
    for (int i = 0; i < 2; ++i)
#pragma unroll
        for (int j = 0; j < 2; ++j) acc[i][j] = (f32x4){0.f, 0.f, 0.f, 0.f};

    const int rowbase = blockIdx.y * 64, colbase = blockIdx.x * 64;

    for (int kt = k0; kt < k0 + klen; kt += 32) {
        gload16(Ab + (size_t)(rowbase + srow) * K + kt + scc * 8, As + w * 512);
        gload16(Bb + (size_t)(colbase + srow) * K + kt + scc * 8, Bs + w * 512);
        __syncthreads();
        s16x8 af[2], bf[2];
#pragma unroll
        for (int i = 0; i < 2; ++i)
            af[i] = *(const s16x8*)&As[(wr * 32 + i * 16 + lr) * 32 + lg * 8];
#pragma unroll
        for (int j = 0; j < 2; ++j)
            bf[j] = *(const s16x8*)&Bs[(wc * 32 + j * 16 + lr) * 32 + lg * 8];
#pragma unroll
        for (int i = 0; i < 2; ++i)
#pragma unroll
            for (int j = 0; j < 2; ++j)
                acc[i][j] = __builtin_amdgcn_mfma_f32_16x16x32_bf16(af[i], bf[j], acc[i][j], 0, 0, 0);
        __syncthreads();
    }

    // C/D layout: col=lane&15, row=(lane>>4)*4+reg (m89-verified)
    if (MODE == 0) {
        float* C = (float*)Cv + (size_t)b * sC;
#pragma unroll
        for (int i = 0; i < 2; ++i)
#pragma unroll
            for (int j = 0; j < 2; ++j) {
                int col = colbase + wc * 32 + j * 16 + lr;
#pragma unroll
                for (int r = 0; r < 4; ++r) {
                    int row = rowbase + wr * 32 + i * 16 + lg * 4 + r;
                    atomicAdd(&C[(size_t)row * N + col], acc[i][j][r]);
                }
            }
    } else {
        unsigned short* C = (unsigned short*)Cv + (size_t)b * sC;
#pragma unroll
        for (int i = 0; i < 2; ++i)
#pragma unroll
            for (int j = 0; j < 2; ++j) {
                int col = colbase + wc * 32 + j * 16 + lr;
#pragma unroll
                for (int r = 0; r < 4; ++r) {
                    int row = rowbase + wr * 32 + i * 16 + lg * 4 + r;
                    C[(size_t)row * N + col] = f2bf(acc[i][j][r]);
                }
            }
    }
}

// ---------- 128x128-tile MFMA GEMM (pass 4: M=2048 -> 512 blocks, f32+bias out) ----------
__global__ __launch_bounds__(256, 2) void gemm_bt_k(const unsigned short* __restrict__ A,
                                                    const unsigned short* __restrict__ Bm,
                                                    float* __restrict__ Cv,
                                                    const float* __restrict__ bias,
                                                    int M, int N, int K,
                                                    long long sA, long long sB, long long sC) {
    __shared__ unsigned short As[128 * 32], Bs[128 * 32];
    int b = blockIdx.z;
    const unsigned short* Ab = A + (size_t)b * sA;
    const unsigned short* Bb = Bm + (size_t)b * sB;
    int tm = blockIdx.y, tn = blockIdx.x;
    int tid = threadIdx.x, w = tid >> 6, l = tid & 63;
    int wr = w >> 1, wc = w & 1;
    int lr = l & 15, lg = l >> 4;

    f32x4 acc[4][4];
#pragma unroll
    for (int i = 0; i < 4; ++i)
#pragma unroll
        for (int j = 0; j < 4; ++j) acc[i][j] = (f32x4){0.f, 0.f, 0.f, 0.f};

    const int rowbase = tm * 128, colbase = tn * 128;

    for (int kt = 0; kt < K; kt += 32) {
#pragma unroll
        for (int i = 0; i < 2; ++i) {
            int ci = (i * 4 + w) * 64 + l;
            int row = ci >> 2, cc = ci & 3;
            gload16(Ab + (size_t)(rowbase + row) * K + kt + cc * 8, As + (i * 4 + w) * 512);
            gload16(Bb + (size_t)(colbase + row) * K + kt + cc * 8, Bs + (i * 4 + w) * 512);
        }
        __syncthreads();
        s16x8 af[4], bf[4];
#pragma unroll
        for (int i = 0; i < 4; ++i)
            af[i] = *(const s16x8*)&As[(wr * 64 + i * 16 + lr) * 32 + lg * 8];
#pragma unroll
        for (int j = 0; j < 4; ++j)
            bf[j] = *(const s16x8*)&Bs[(wc * 64 + j * 16 + lr) * 32 + lg * 8];
#pragma unroll
        for (int i = 0; i < 4; ++i)
#pragma unroll
            for (int j = 0; j < 4; ++j)
                acc[i][j] = __builtin_amdgcn_mfma_f32_16x16x32_bf16(af[i], bf[j], acc[i][j], 0, 0, 0);
        __syncthreads();
    }

    float* C = Cv + (size_t)b * sC;
#pragma unroll
    for (int i = 0; i < 4; ++i)
#pragma unroll
        for (int j = 0; j < 4; ++j) {
            int col = colbase + wc * 64 + j * 16 + lr;
            float bv = bias[col];
#pragma unroll
            for (int r = 0; r < 4; ++r) {
                int row = rowbase + wr * 64 + i * 16 + lg * 4 + r;
                C[(size_t)row * N + col] = acc[i][j][r] + bv;
            }
        }
}

extern "C" void kernel_launch(void* const* d_in, const int* in_sizes, int n_in,
                              void* d_out, int out_size, void* d_ws, size_t ws_size,
                              hipStream_t stream) {
    const float* x    = (const float*)d_in[0];   // [8,2048,512]
    const float* x2   = (const float*)d_in[1];   // [8,2048,512]
    const float* W    = (const float*)d_in[2];   // [512,512]
    const float* bias = (const float*)d_in[3];   // [512]
    float* out = (float*)d_out;                  // [8,2048,512] f32

    // workspace carve — ~65 MB
    unsigned short* Kt  = (unsigned short*)d_ws;         // [8][512][2048] bf16
    unsigned short* Qt  = Kt + 8388608;                  // [8][512][2048]
    unsigned short* xb  = Qt + 8388608;                  // [8][2048][512]
    unsigned short* Wb  = xb + 8388608;                  // [512][512]
    unsigned short* KQb = Wb + 262144;                   // [8][512][512] bf16
    unsigned short* Mt  = KQb + 2097152;                 // [8][512][512] bf16
    float* KQf = (float*)(Mt + 2097152);                 // [8][512][512] f32 (split-K acc)
    float* qs  = KQf + 2097152;                          // [8*512]  (adjacent: one memset)
    float* rks = qs + 4096;                              // [8*2048]

    // zero split-K accumulator + qs in one memset (ws is re-poisoned 0xAA every call)
    hipMemsetAsync(KQf, 0, (2097152 + 4096) * sizeof(float), stream);

    // denominators: single x2 read
    fused_sums_k<<<dim3(B_ * N_ / 32), 256, 0, stream>>>(x2, rks, qs);

    // softmax + transpose -> Kt, Qt (bf16, [d][m])
    softmax_tr_k<<<dim3(N_ / 64, D_ / 64, B_), 256, 0, stream>>>(x2, rks, qs, Kt, Qt);

    // bf16 copies of x and W
    cvt_bf16_k<<<dim3(4096), 256, 0, stream>>>(x, xb);
    cvt_bf16_k<<<dim3(128), 256, 0, stream>>>(W, Wb);

    // pass 2: KQ[i][j] = sum_m Kt[i][m]*Qt[j][m]   (512x512xK2048, split-K 2 -> 1024 blocks)
    gemm64_k<0><<<dim3(8, 8, B_ * 2), 256, 0, stream>>>(
        Kt, Qt, KQf, 512, 512, 2048, 2,
        (long long)512 * 2048, (long long)512 * 2048, (long long)512 * 512);

    // KQ f32 -> bf16
    cvt_bf16_k<<<dim3(1024), 256, 0, stream>>>(KQf, KQb);

    // pass 3: Mt[e][i] = sum_j W[e][j]*KQ[i][j]    (512x512x512 -> 512 blocks)
    gemm64_k<2><<<dim3(8, 8, B_), 256, 0, stream>>>(
        Wb, KQb, Mt, 512, 512, 512, 1,
        0LL, (long long)512 * 512, (long long)512 * 512);

    // pass 4: out[n][e] = sum_i xb[n][i]*Mt[e][i] + b[e]  (2048x512x512 -> 512 blocks)
    gemm_bt_k<<<dim3(4, 16, B_), 256, 0, stream>>>(
        xb, Mt, out, bias, 2048, 512, 512,
        (long long)2048 * 512, (long long)512 * 512, (long long)2048 * 512);
}

// Round 4
// 183.118 us; speedup vs baseline: 1.1358x; 1.0566x over previous
//
#include <hip/hip_runtime.h>

// CrossAttention restructured:  out = x @ ((G/qs) @ W^T) + b,  G = F^T F (SYRK form)
//   F[m,d] = exp(x2[m,d]) * sqrt(rks[m]);  rks = 1/rowsum(exp), qs = colsum(exp)
// R4: single F matrix replaces Kt/Qt; x cvt fused into pass4 (f32 LDS staging);
//     split-K via disjoint partial buffers (no atomics/memset); reversed-order
//     softmax pass for L3 reuse of x2.

typedef __attribute__((ext_vector_type(8))) short          s16x8;
typedef __attribute__((ext_vector_type(8))) unsigned short u16x8;
typedef __attribute__((ext_vector_type(4))) float          f32x4;

#define B_ 8
#define N_ 2048
#define D_ 512

__device__ inline unsigned short f2bf(float f) {  // f32 -> bf16 RNE
    unsigned u = __float_as_uint(f);
    u += 0x7FFFu + ((u >> 16) & 1u);
    return (unsigned short)(u >> 16);
}

// ---------- fused denominators: one x2 read -> rsq (sqrt(1/rowsum)), qs (col sums) ----------
__global__ __launch_bounds__(256) void fused_sums_k(const float* __restrict__ x2,
                                                    float* __restrict__ rsq,
                                                    float* __restrict__ qs) {
    __shared__ float cp[4][512];
    int w = threadIdx.x >> 6, l = threadIdx.x & 63;
    int rbase = blockIdx.x * 32;
    int b = rbase / N_;
    const int c0 = l * 8;
    float colacc[8] = {0.f, 0.f, 0.f, 0.f, 0.f, 0.f, 0.f, 0.f};
#pragma unroll
    for (int rr = 0; rr < 8; ++rr) {
        int r = rbase + w * 8 + rr;
        const float* p = x2 + (size_t)r * D_ + c0;
        float4 a = *(const float4*)p;
        float4 bb = *(const float4*)(p + 4);
        float e0 = __expf(a.x), e1 = __expf(a.y), e2 = __expf(a.z), e3 = __expf(a.w);
        float e4 = __expf(bb.x), e5 = __expf(bb.y), e6 = __expf(bb.z), e7 = __expf(bb.w);
        float s = e0 + e1 + e2 + e3 + e4 + e5 + e6 + e7;
#pragma unroll
        for (int off = 1; off < 64; off <<= 1) s += __shfl_xor(s, off);
        if (l == 0) rsq[r] = sqrtf(1.0f / s);         // only consumer is F-scaling
        colacc[0] += e0; colacc[1] += e1; colacc[2] += e2; colacc[3] += e3;
        colacc[4] += e4; colacc[5] += e5; colacc[6] += e6; colacc[7] += e7;
    }
#pragma unroll
    for (int c = 0; c < 8; ++c) cp[w][c0 + c] = colacc[c];
    __syncthreads();
    for (int c = threadIdx.x; c < 512; c += 256) {
        float s = cp[0][c] + cp[1][c] + cp[2][c] + cp[3][c];
        atomicAdd(&qs[b * D_ + c], s);
    }
}

// ---------- F^T build: Ft[b][d][m] = bf16(exp(x2[b,m,d]) * rsq[b,m]) ----------
// Blocks run in REVERSE memory order: x2's tail is still L3-resident from fused_sums.
__global__ __launch_bounds__(256) void softmax_ft_k(const float* __restrict__ x2,
                                                    const float* __restrict__ rsq,
                                                    unsigned short* __restrict__ Ft) {
    __shared__ unsigned short ft[64][65];
    int b  = 7 - blockIdx.z;
    int d0 = (7 - blockIdx.y) * 64;
    int m0 = (31 - blockIdx.x) * 64;
    int tx = threadIdx.x & 63, w = threadIdx.x >> 6;
#pragma unroll
    for (int it = 0; it < 16; ++it) {
        int row = w * 16 + it;
        float v = x2[((size_t)b * N_ + m0 + row) * D_ + d0 + tx];
        float sc = rsq[b * N_ + m0 + row];              // wave-uniform scalar
        ft[tx][row] = f2bf(__expf(v) * sc);
    }
    __syncthreads();
#pragma unroll
    for (int it = 0; it < 16; ++it) {
        int dr = w * 16 + it;
        Ft[((size_t)b * D_ + d0 + dr) * N_ + m0 + tx] = ft[dr][tx];
    }
}

// ---------- f32 -> bf16 bulk convert (W only) ----------
__global__ __launch_bounds__(256) void cvt_bf16_k(const float* __restrict__ in,
                                                  unsigned short* __restrict__ out) {
    size_t i = ((size_t)blockIdx.x * 256 + threadIdx.x) * 8;
    float4 a = *(const float4*)(in + i);
    float4 b = *(const float4*)(in + i + 4);
    u16x8 o;
    o[0] = f2bf(a.x); o[1] = f2bf(a.y); o[2] = f2bf(a.z); o[3] = f2bf(a.w);
    o[4] = f2bf(b.x); o[5] = f2bf(b.y); o[6] = f2bf(b.z); o[7] = f2bf(b.w);
    *(u16x8*)(out + i) = o;
}

// ---------- KQb[b][i][j] = bf16((P0+P1)[b][i][j] / qs[b][j]) ----------
__global__ __launch_bounds__(256) void cvt_kq_k(const float* __restrict__ P,
                                                const float* __restrict__ qs,
                                                unsigned short* __restrict__ KQb) {
    size_t o = ((size_t)blockIdx.x * 256 + threadIdx.x) * 8;   // over B*512*512
    int b = (int)(o >> 18);
    size_t off = o & 262143;
    int j0 = (int)(o & 511);
    const float* p0 = P + ((size_t)b * 2) * 262144 + off;
    const float* p1 = p0 + 262144;
    float4 a0 = *(const float4*)p0,        a1 = *(const float4*)(p0 + 4);
    float4 c0 = *(const float4*)p1,        c1 = *(const float4*)(p1 + 4);
    float4 q0 = *(const float4*)(qs + b * D_ + j0);
    float4 q1 = *(const float4*)(qs + b * D_ + j0 + 4);
    u16x8 r;
    r[0] = f2bf((a0.x + c0.x) / q0.x); r[1] = f2bf((a0.y + c0.y) / q0.y);
    r[2] = f2bf((a0.z + c0.z) / q0.z); r[3] = f2bf((a0.w + c0.w) / q0.w);
    r[4] = f2bf((a1.x + c1.x) / q1.x); r[5] = f2bf((a1.y + c1.y) / q1.y);
    r[6] = f2bf((a1.z + c1.z) / q1.z); r[7] = f2bf((a1.w + c1.w) / q1.w);
    *(u16x8*)(KQb + o) = r;
}

__device__ inline void gload16(const unsigned short* g, unsigned short* l) {
    __builtin_amdgcn_global_load_lds((const __attribute__((address_space(1))) void*)g,
                                     (__attribute__((address_space(3))) void*)l, 16, 0, 0);
}
__device__ inline void gload16f(const float* g, float* l) {
    __builtin_amdgcn_global_load_lds((const __attribute__((address_space(1))) void*)g,
                                     (__attribute__((address_space(3))) void*)l, 16, 0, 0);
}

// ---------- 64x64-tile MFMA GEMM. C = A[M,K] * B[N,K]^T ----------
// MODE 0: f32 partials at Cv + blockIdx.z*sC (split-K, disjoint).  MODE 2: bf16 at b*sC.
template <int MODE>
__global__ __launch_bounds__(256, 4) void gemm64_k(const unsigned short* __restrict__ A,
                                                   const unsigned short* __restrict__ Bm,
                                                   void* __restrict__ Cv,
                                                   int M, int N, int K, int nsplit,
                                                   long long sA, long long sB, long long sC) {
    __shared__ unsigned short As[64 * 32], Bs[64 * 32];
    int b = blockIdx.z / nsplit, ks = blockIdx.z % nsplit;
    int klen = K / nsplit, k0 = ks * klen;
    const unsigned short* Ab = A + (size_t)b * sA;
    const unsigned short* Bb = Bm + (size_t)b * sB;
    int tid = threadIdx.x, w = tid >> 6, l = tid & 63;
    int wr = w >> 1, wc = w & 1;
    int lr = l & 15, lg = l >> 4;
    int srow = tid >> 2, scc = tid & 3;

    f32x4 acc[2][2];
#pragma unroll
    for (int i = 0; i < 2; ++i)
#pragma unroll
        for (int j = 0; j < 2; ++j) acc[i][j] = (f32x4){0.f, 0.f, 0.f, 0.f};

    const int rowbase = blockIdx.y * 64, colbase = blockIdx.x * 64;

    for (int kt = k0; kt < k0 + klen; kt += 32) {
        gload16(Ab + (size_t)(rowbase + srow) * K + kt + scc * 8, As + w * 512);
        gload16(Bb + (size_t)(colbase + srow) * K + kt + scc * 8, Bs + w * 512);
        __syncthreads();
        s16x8 af[2], bf[2];
#pragma unroll
        for (int i = 0; i < 2; ++i)
            af[i] = *(const s16x8*)&As[(wr * 32 + i * 16 + lr) * 32 + lg * 8];
#pragma unroll
        for (int j = 0; j < 2; ++j)
            bf[j] = *(const s16x8*)&Bs[(wc * 32 + j * 16 + lr) * 32 + lg * 8];
#pragma unroll
        for (int i = 0; i < 2; ++i)
#pragma unroll
            for (int j = 0; j < 2; ++j)
                acc[i][j] = __builtin_amdgcn_mfma_f32_16x16x32_bf16(af[i], bf[j], acc[i][j], 0, 0, 0);
        __syncthreads();
    }

    if (MODE == 0) {
        float* C = (float*)Cv + (size_t)blockIdx.z * sC;
#pragma unroll
        for (int i = 0; i < 2; ++i)
#pragma unroll
            for (int j = 0; j < 2; ++j) {
                int col = colbase + wc * 32 + j * 16 + lr;
#pragma unroll
                for (int r = 0; r < 4; ++r) {
                    int row = rowbase + wr * 32 + i * 16 + lg * 4 + r;
                    C[(size_t)row * N + col] = acc[i][j][r];
                }
            }
    } else {
        unsigned short* C = (unsigned short*)Cv + (size_t)b * sC;
#pragma unroll
        for (int i = 0; i < 2; ++i)
#pragma unroll
            for (int j = 0; j < 2; ++j) {
                int col = colbase + wc * 32 + j * 16 + lr;
#pragma unroll
                for (int r = 0; r < 4; ++r) {
                    int row = rowbase + wr * 32 + i * 16 + lg * 4 + r;
                    C[(size_t)row * N + col] = f2bf(acc[i][j][r]);
                }
            }
    }
}

// ---------- pass 4: out = x(f32, staged+cvt in-kernel) @ Mt^T + bias ----------
__global__ __launch_bounds__(256, 2) void gemm_xf32_k(const float* __restrict__ X,
                                                      const unsigned short* __restrict__ Bm,
                                                      float* __restrict__ Out,
                                                      const float* __restrict__ bias) {
    __shared__ float Asf[128 * 32];           // 16 KB
    __shared__ unsigned short Bs[128 * 32];   // 8 KB
    int b = blockIdx.z;
    const float* Ab = X + (size_t)b * ((size_t)N_ * D_);
    const unsigned short* Bb = Bm + (size_t)b * ((size_t)D_ * D_);
    int tm = blockIdx.y, tn = blockIdx.x;
    int tid = threadIdx.x, w = tid >> 6, l = tid & 63;
    int wr = w >> 1, wc = w & 1;
    int lr = l & 15, lg = l >> 4;

    f32x4 acc[4][4];
#pragma unroll
    for (int i = 0; i < 4; ++i)
#pragma unroll
        for (int j = 0; j < 4; ++j) acc[i][j] = (f32x4){0.f, 0.f, 0.f, 0.f};

    const int rowbase = tm * 128, colbase = tn * 128;

    for (int kt = 0; kt < D_; kt += 32) {
        // A (f32): 128 rows x 32 cols = 1024 x 16B chunks; linear LDS dest
#pragma unroll
        for (int i = 0; i < 4; ++i) {
            int ci = (i * 4 + w) * 64 + l;            // 0..1023
            int row = ci >> 3, cc = ci & 7;
            gload16f(Ab + (size_t)(rowbase + row) * D_ + kt + cc * 4, Asf + (i * 4 + w) * 256);
        }
        // B (bf16): 128 rows x 32 cols = 512 x 16B chunks
#pragma unroll
        for (int i = 0; i < 2; ++i) {
            int ci = (i * 4 + w) * 64 + l;
            int row = ci >> 2, cc = ci & 3;
            gload16(Bb + (size_t)(colbase + row) * D_ + kt + cc * 8, Bs + (i * 4 + w) * 512);
        }
        __syncthreads();
        s16x8 af[4], bf[4];
#pragma unroll
        for (int i = 0; i < 4; ++i) {
            const float* ap = &Asf[(wr * 64 + i * 16 + lr) * 32 + lg * 8];
            f32x4 a0 = *(const f32x4*)ap, a1 = *(const f32x4*)(ap + 4);
            s16x8 t;
            t[0] = (short)f2bf(a0[0]); t[1] = (short)f2bf(a0[1]);
            t[2] = (short)f2bf(a0[2]); t[3] = (short)f2bf(a0[3]);
            t[4] = (short)f2bf(a1[0]); t[5] = (short)f2bf(a1[1]);
            t[6] = (short)f2bf(a1[2]); t[7] = (short)f2bf(a1[3]);
            af[i] = t;
        }
#pragma unroll
        for (int j = 0; j < 4; ++j)
            bf[j] = *(const s16x8*)&Bs[(wc * 64 + j * 16 + lr) * 32 + lg * 8];
#pragma unroll
        for (int i = 0; i < 4; ++i)
#pragma unroll
            for (int j = 0; j < 4; ++j)
                acc[i][j] = __builtin_amdgcn_mfma_f32_16x16x32_bf16(af[i], bf[j], acc[i][j], 0, 0, 0);
        __syncthreads();
    }

    float* C = Out + (size_t)b * ((size_t)N_ * D_);
#pragma unroll
    for (int i = 0; i < 4; ++i)
#pragma unroll
        for (int j = 0; j < 4; ++j) {
            int col = colbase + wc * 64 + j * 16 + lr;
            float bv = bias[col];
#pragma unroll
            for (int r = 0; r < 4; ++r) {
                int row = rowbase + wr * 64 + i * 16 + lg * 4 + r;
                C[(size_t)row * D_ + col] = acc[i][j][r] + bv;
            }
        }
}

extern "C" void kernel_launch(void* const* d_in, const int* in_sizes, int n_in,
                              void* d_out, int out_size, void* d_ws, size_t ws_size,
                              hipStream_t stream) {
    const float* x    = (const float*)d_in[0];   // [8,2048,512]
    const float* x2   = (const float*)d_in[1];   // [8,2048,512]
    const float* W    = (const float*)d_in[2];   // [512,512]
    const float* bias = (const float*)d_in[3];   // [512]
    float* out = (float*)d_out;                  // [8,2048,512] f32

    // workspace carve — ~43 MB
    unsigned short* Ft  = (unsigned short*)d_ws;         // [8][512][2048] bf16
    unsigned short* Wb  = Ft + 8388608;                  // [512][512]
    unsigned short* KQb = Wb + 262144;                   // [8][512][512] bf16
    unsigned short* Mt  = KQb + 2097152;                 // [8][512][512] bf16
    float* P   = (float*)(Mt + 2097152);                 // [8][2][512][512] f32 split-K partials
    float* qs  = P + 4194304;                            // [8*512]
    float* rsq = qs + 4096;                              // [8*2048]

    hipMemsetAsync(qs, 0, (size_t)B_ * D_ * sizeof(float), stream);

    // denominators: single x2 read
    fused_sums_k<<<dim3(B_ * N_ / 32), 256, 0, stream>>>(x2, rsq, qs);

    // F^T (bf16, [d][m]), reverse block order for L3 reuse of x2
    softmax_ft_k<<<dim3(N_ / 64, D_ / 64, B_), 256, 0, stream>>>(x2, rsq, Ft);

    // bf16 W
    cvt_bf16_k<<<dim3(128), 256, 0, stream>>>(W, Wb);

    // pass 2 (SYRK): P[z] = Ft(64-rows) . Ft(64-cols)^T over half-K each
    gemm64_k<0><<<dim3(8, 8, B_ * 2), 256, 0, stream>>>(
        Ft, Ft, P, 512, 512, 2048, 2,
        (long long)512 * 2048, (long long)512 * 2048, (long long)512 * 512);

    // KQ = (P0+P1)/qs -> bf16
    cvt_kq_k<<<dim3(1024), 256, 0, stream>>>(P, qs, KQb);

    // pass 3: Mt[e][i] = sum_j Wb[e][j]*KQb[i][j]
    gemm64_k<2><<<dim3(8, 8, B_), 256, 0, stream>>>(
        Wb, KQb, Mt, 512, 512, 512, 1,
        0LL, (long long)512 * 512, (long long)512 * 512);

    // pass 4: out[n][e] = sum_i x[n][i]*Mt[e][i] + b[e]  (f32 A staged in-kernel)
    gemm_xf32_k<<<dim3(4, 16, B_), 256, 0, stream>>>(x, Mt, out, bias);
}

// Round 8
// 174.421 us; speedup vs baseline: 1.1925x; 1.0499x over previous
//
#include <hip/hip_runtime.h>

// CrossAttention restructured:  out = x @ ((G/qs) @ W^T) + b,  G = F^T F
//   F[m,d] = exp(x2[m,d]) * rsqrt(rowsum(exp));  qs = colsum(exp)
// R5: single-pass softmax (one x2 read, fused row sums + transpose);
//     pass2 -> 128^2 tiles with split-K=4 disjoint f32 partials.

typedef __attribute__((ext_vector_type(8))) short          s16x8;
typedef __attribute__((ext_vector_type(8))) unsigned short u16x8;
typedef __attribute__((ext_vector_type(4))) float          f32x4;

#define B_ 8
#define N_ 2048
#define D_ 512

__device__ inline unsigned short f2bf(float f) {  // f32 -> bf16 RNE
    unsigned u = __float_as_uint(f);
    u += 0x7FFFu + ((u >> 16) & 1u);
    return (unsigned short)(u >> 16);
}

// ---------- one-pass softmax: reads x2 once -> Ft (bf16 [d][m], scaled), qs col sums ----------
// block = 64 rows x 512 cols; wave holds a full row (64 lanes x 8 elems).
__global__ __launch_bounds__(256) void softmax_fused_k(const float* __restrict__ x2,
                                                       unsigned short* __restrict__ Ft,
                                                       float* __restrict__ qs) {
    __shared__ unsigned short ft[64][522];   // [m][d], pad 522: transposed reads conflict-free
    __shared__ float cp[4][512];             // per-wave column partials
    int b = blockIdx.y, m0 = blockIdx.x * 64;
    int w = threadIdx.x >> 6, l = threadIdx.x & 63;
    const int c0 = l * 8;
    float colacc[8] = {0.f, 0.f, 0.f, 0.f, 0.f, 0.f, 0.f, 0.f};
#pragma unroll
    for (int it = 0; it < 16; ++it) {
        int row = w * 16 + it;
        const float* p = x2 + ((size_t)b * N_ + m0 + row) * D_ + c0;
        float4 a = *(const float4*)p;
        float4 bb = *(const float4*)(p + 4);
        float e0 = __expf(a.x), e1 = __expf(a.y), e2 = __expf(a.z), e3 = __expf(a.w);
        float e4 = __expf(bb.x), e5 = __expf(bb.y), e6 = __expf(bb.z), e7 = __expf(bb.w);
        float s = e0 + e1 + e2 + e3 + e4 + e5 + e6 + e7;
#pragma unroll
        for (int off = 1; off < 64; off <<= 1) s += __shfl_xor(s, off);
        float rv = rsqrtf(s);                 // sqrt(1/rowsum)
        u16x8 o;
        o[0] = f2bf(e0 * rv); o[1] = f2bf(e1 * rv); o[2] = f2bf(e2 * rv); o[3] = f2bf(e3 * rv);
        o[4] = f2bf(e4 * rv); o[5] = f2bf(e5 * rv); o[6] = f2bf(e6 * rv); o[7] = f2bf(e7 * rv);
        *(u16x8*)&ft[row][c0] = o;            // contiguous 16B/lane: conflict-free
        colacc[0] += e0; colacc[1] += e1; colacc[2] += e2; colacc[3] += e3;
        colacc[4] += e4; colacc[5] += e5; colacc[6] += e6; colacc[7] += e7;
    }
#pragma unroll
    for (int c = 0; c < 8; ++c) cp[w][c0 + c] = colacc[c];
    __syncthreads();
    for (int c = threadIdx.x; c < 512; c += 256) {
        float s = cp[0][c] + cp[1][c] + cp[2][c] + cp[3][c];
        atomicAdd(&qs[b * D_ + c], s);
    }
    // transposed write-out: thread handles d = tid and tid+256; 64 m each
#pragma unroll
    for (int half = 0; half < 2; ++half) {
        int d = threadIdx.x + half * 256;
        unsigned short* dst = Ft + ((size_t)b * D_ + d) * N_ + m0;
#pragma unroll
        for (int mv = 0; mv < 8; ++mv) {
            u16x8 o;
#pragma unroll
            for (int k = 0; k < 8; ++k) o[k] = ft[mv * 8 + k][d];
            *(u16x8*)(dst + mv * 8) = o;
        }
    }
}

// ---------- f32 -> bf16 bulk convert (W only) ----------
__global__ __launch_bounds__(256) void cvt_bf16_k(const float* __restrict__ in,
                                                  unsigned short* __restrict__ out) {
    size_t i = ((size_t)blockIdx.x * 256 + threadIdx.x) * 8;
    float4 a = *(const float4*)(in + i);
    float4 b = *(const float4*)(in + i + 4);
    u16x8 o;
    o[0] = f2bf(a.x); o[1] = f2bf(a.y); o[2] = f2bf(a.z); o[3] = f2bf(a.w);
    o[4] = f2bf(b.x); o[5] = f2bf(b.y); o[6] = f2bf(b.z); o[7] = f2bf(b.w);
    *(u16x8*)(out + i) = o;
}

// ---------- KQb[b][i][j] = bf16(sum_{s<4} P[b,s][i][j] / qs[b][j]) ----------
__global__ __launch_bounds__(256) void cvt_kq_k(const float* __restrict__ P,
                                                const float* __restrict__ qs,
                                                unsigned short* __restrict__ KQb) {
    size_t o = ((size_t)blockIdx.x * 256 + threadIdx.x) * 8;   // over B*512*512
    int b = (int)(o >> 18);
    size_t off = o & 262143;
    int j0 = (int)(o & 511);
    const float* base = P + (size_t)b * 4 * 262144 + off;
    float4 s0 = {0.f, 0.f, 0.f, 0.f}, s1 = {0.f, 0.f, 0.f, 0.f};
#pragma unroll
    for (int s = 0; s < 4; ++s) {
        float4 a0 = *(const float4*)(base + (size_t)s * 262144);
        float4 a1 = *(const float4*)(base + (size_t)s * 262144 + 4);
        s0.x += a0.x; s0.y += a0.y; s0.z += a0.z; s0.w += a0.w;
        s1.x += a1.x; s1.y += a1.y; s1.z += a1.z; s1.w += a1.w;
    }
    float4 q0 = *(const float4*)(qs + b * D_ + j0);
    float4 q1 = *(const float4*)(qs + b * D_ + j0 + 4);
    u16x8 r;
    r[0] = f2bf(s0.x / q0.x); r[1] = f2bf(s0.y / q0.y);
    r[2] = f2bf(s0.z / q0.z); r[3] = f2bf(s0.w / q0.w);
    r[4] = f2bf(s1.x / q1.x); r[5] = f2bf(s1.y / q1.y);
    r[6] = f2bf(s1.z / q1.z); r[7] = f2bf(s1.w / q1.w);
    *(u16x8*)(KQb + o) = r;
}

__device__ inline void gload16(const unsigned short* g, unsigned short* l) {
    __builtin_amdgcn_global_load_lds((const __attribute__((address_space(1))) void*)g,
                                     (__attribute__((address_space(3))) void*)l, 16, 0, 0);
}
__device__ inline void gload16f(const float* g, float* l) {
    __builtin_amdgcn_global_load_lds((const __attribute__((address_space(1))) void*)g,
                                     (__attribute__((address_space(3))) void*)l, 16, 0, 0);
}

// ---------- pass 2 (SYRK): 128^2 tiles, split-K=4, f32 partials P[z][512][512] ----------
__global__ __launch_bounds__(256, 2) void gemm128_p2_k(const unsigned short* __restrict__ Ft,
                                                       float* __restrict__ P) {
    __shared__ unsigned short As[128 * 32], Bs[128 * 32];
    const int nsplit = 4, K = N_;
    int z = blockIdx.z, b = z >> 2, ks = z & 3;
    int klen = K / nsplit, k0 = ks * klen;
    const unsigned short* Ab = Ft + (size_t)b * ((size_t)D_ * N_);
    int tid = threadIdx.x, w = tid >> 6, l = tid & 63;
    int wr = w >> 1, wc = w & 1;
    int lr = l & 15, lg = l >> 4;

    f32x4 acc[4][4];
#pragma unroll
    for (int i = 0; i < 4; ++i)
#pragma unroll
        for (int j = 0; j < 4; ++j) acc[i][j] = (f32x4){0.f, 0.f, 0.f, 0.f};

    const int rowbase = blockIdx.y * 128, colbase = blockIdx.x * 128;

    for (int kt = k0; kt < k0 + klen; kt += 32) {
#pragma unroll
        for (int i = 0; i < 2; ++i) {
            int ci = (i * 4 + w) * 64 + l;
            int row = ci >> 2, cc = ci & 3;
            gload16(Ab + (size_t)(rowbase + row) * K + kt + cc * 8, As + (i * 4 + w) * 512);
            gload16(Ab + (size_t)(colbase + row) * K + kt + cc * 8, Bs + (i * 4 + w) * 512);
        }
        __syncthreads();
        s16x8 af[4], bf[4];
#pragma unroll
        for (int i = 0; i < 4; ++i)
            af[i] = *(const s16x8*)&As[(wr * 64 + i * 16 + lr) * 32 + lg * 8];
#pragma unroll
        for (int j = 0; j < 4; ++j)
            bf[j] = *(const s16x8*)&Bs[(wc * 64 + j * 16 + lr) * 32 + lg * 8];
#pragma unroll
        for (int i = 0; i < 4; ++i)
#pragma unroll
            for (int j = 0; j < 4; ++j)
                acc[i][j] = __builtin_amdgcn_mfma_f32_16x16x32_bf16(af[i], bf[j], acc[i][j], 0, 0, 0);
        __syncthreads();
    }

    float* C = P + (size_t)z * 262144;
#pragma unroll
    for (int i = 0; i < 4; ++i)
#pragma unroll
        for (int j = 0; j < 4; ++j) {
            int col = colbase + wc * 64 + j * 16 + lr;
#pragma unroll
            for (int r = 0; r < 4; ++r) {
                int row = rowbase + wr * 64 + i * 16 + lg * 4 + r;
                C[(size_t)row * D_ + col] = acc[i][j][r];
            }
        }
}

// ---------- pass 3: 64x64 tiles. Mt[e][i] = sum_j Wb[e][j]*KQb[i][j], bf16 out ----------
__global__ __launch_bounds__(256, 4) void gemm64_k(const unsigned short* __restrict__ A,
                                                   const unsigned short* __restrict__ Bm,
                                                   unsigned short* __restrict__ Cv,
                                                   int K, long long sA, long long sB, long long sC) {
    __shared__ unsigned short As[64 * 32], Bs[64 * 32];
    int b = blockIdx.z;
    const unsigned short* Ab = A + (size_t)b * sA;
    const unsigned short* Bb = Bm + (size_t)b * sB;
    int tid = threadIdx.x, w = tid >> 6, l = tid & 63;
    int wr = w >> 1, wc = w & 1;
    int lr = l & 15, lg = l >> 4;
    int srow = tid >> 2, scc = tid & 3;

    f32x4 acc[2][2];
#pragma unroll
    for (int i = 0; i < 2; ++i)
#pragma unroll
        for (int j = 0; j < 2; ++j) acc[i][j] = (f32x4){0.f, 0.f, 0.f, 0.f};

    const int rowbase = blockIdx.y * 64, colbase = blockIdx.x * 64;

    for (int kt = 0; kt < K; kt += 32) {
        gload16(Ab + (size_t)(rowbase + srow) * K + kt + scc * 8, As + w * 512);
        gload16(Bb + (size_t)(colbase + srow) * K + kt + scc * 8, Bs + w * 512);
        __syncthreads();
        s16x8 af[2], bf[2];
#pragma unroll
        for (int i = 0; i < 2; ++i)
            af[i] = *(const s16x8*)&As[(wr * 32 + i * 16 + lr) * 32 + lg * 8];
#pragma unroll
        for (int j = 0; j < 2; ++j)
            bf[j] = *(const s16x8*)&Bs[(wc * 32 + j * 16 + lr) * 32 + lg * 8];
#pragma unroll
        for (int i = 0; i < 2; ++i)
#pragma unroll
            for (int j = 0; j < 2; ++j)
                acc[i][j] = __builtin_amdgcn_mfma_f32_16x16x32_bf16(af[i], bf[j], acc[i][j], 0, 0, 0);
        __syncthreads();
    }

    unsigned short* C = Cv + (size_t)b * sC;
#pragma unroll
    for (int i = 0; i < 2; ++i)
#pragma unroll
        for (int j = 0; j < 2; ++j) {
            int col = colbase + wc * 32 + j * 16 + lr;
#pragma unroll
            for (int r = 0; r < 4; ++r) {
                int row = rowbase + wr * 32 + i * 16 + lg * 4 + r;
                C[(size_t)row * D_ + col] = f2bf(acc[i][j][r]);
            }
        }
}

// ---------- pass 4: out = x(f32, staged+cvt in-kernel) @ Mt^T + bias ----------
__global__ __launch_bounds__(256, 2) void gemm_xf32_k(const float* __restrict__ X,
                                                      const unsigned short* __restrict__ Bm,
                                                      float* __restrict__ Out,
                                                      const float* __restrict__ bias) {
    __shared__ float Asf[128 * 32];
    __shared__ unsigned short Bs[128 * 32];
    int b = blockIdx.z;
    const float* Ab = X + (size_t)b * ((size_t)N_ * D_);
    const unsigned short* Bb = Bm + (size_t)b * ((size_t)D_ * D_);
    int tm = blockIdx.y, tn = blockIdx.x;
    int tid = threadIdx.x, w = tid >> 6, l = tid & 63;
    int wr = w >> 1, wc = w & 1;
    int lr = l & 15, lg = l >> 4;

    f32x4 acc[4][4];
#pragma unroll
    for (int i = 0; i < 4; ++i)
#pragma unroll
        for (int j = 0; j < 4; ++j) acc[i][j] = (f32x4){0.f, 0.f, 0.f, 0.f};

    const int rowbase = tm * 128, colbase = tn * 128;

    for (int kt = 0; kt < D_; kt += 32) {
#pragma unroll
        for (int i = 0; i < 4; ++i) {
            int ci = (i * 4 + w) * 64 + l;
            int row = ci >> 3, cc = ci & 7;
            gload16f(Ab + (size_t)(rowbase + row) * D_ + kt + cc * 4, Asf + (i * 4 + w) * 256);
        }
#pragma unroll
        for (int i = 0; i < 2; ++i) {
            int ci = (i * 4 + w) * 64 + l;
            int row = ci >> 2, cc = ci & 3;
            gload16(Bb + (size_t)(colbase + row) * D_ + kt + cc * 8, Bs + (i * 4 + w) * 512);
        }
        __syncthreads();
        s16x8 af[4], bf[4];
#pragma unroll
        for (int i = 0; i < 4; ++i) {
            const float* ap = &Asf[(wr * 64 + i * 16 + lr) * 32 + lg * 8];
            f32x4 a0 = *(const f32x4*)ap, a1 = *(const f32x4*)(ap + 4);
            s16x8 t;
            t[0] = (short)f2bf(a0[0]); t[1] = (short)f2bf(a0[1]);
            t[2] = (short)f2bf(a0[2]); t[3] = (short)f2bf(a0[3]);
            t[4] = (short)f2bf(a1[0]); t[5] = (short)f2bf(a1[1]);
            t[6] = (short)f2bf(a1[2]); t[7] = (short)f2bf(a1[3]);
            af[i] = t;
        }
#pragma unroll
        for (int j = 0; j < 4; ++j)
            bf[j] = *(const s16x8*)&Bs[(wc * 64 + j * 16 + lr) * 32 + lg * 8];
#pragma unroll
        for (int i = 0; i < 4; ++i)
#pragma unroll
            for (int j = 0; j < 4; ++j)
                acc[i][j] = __builtin_amdgcn_mfma_f32_16x16x32_bf16(af[i], bf[j], acc[i][j], 0, 0, 0);
        __syncthreads();
    }

    float* C = Out + (size_t)b * ((size_t)N_ * D_);
#pragma unroll
    for (int i = 0; i < 4; ++i)
#pragma unroll
        for (int j = 0; j < 4; ++j) {
            int col = colbase + wc * 64 + j * 16 + lr;
            float bv = bias[col];
#pragma unroll
            for (int r = 0; r < 4; ++r) {
                int row = rowbase + wr * 64 + i * 16 + lg * 4 + r;
                C[(size_t)row * D_ + col] = acc[i][j][r] + bv;
            }
        }
}

extern "C" void kernel_launch(void* const* d_in, const int* in_sizes, int n_in,
                              void* d_out, int out_size, void* d_ws, size_t ws_size,
                              hipStream_t stream) {
    const float* x    = (const float*)d_in[0];   // [8,2048,512]
    const float* x2   = (const float*)d_in[1];   // [8,2048,512]
    const float* W    = (const float*)d_in[2];   // [512,512]
    const float* bias = (const float*)d_in[3];   // [512]
    float* out = (float*)d_out;                  // [8,2048,512] f32

    // workspace carve — ~57 MB
    unsigned short* Ft  = (unsigned short*)d_ws;         // [8][512][2048] bf16
    unsigned short* Wb  = Ft + 8388608;                  // [512][512]
    unsigned short* KQb = Wb + 262144;                   // [8][512][512] bf16
    unsigned short* Mt  = KQb + 2097152;                 // [8][512][512] bf16
    float* P   = (float*)(Mt + 2097152);                 // [8][4][512][512] f32 split-K partials
    float* qs  = P + 8388608;                            // [8*512]

    hipMemsetAsync(qs, 0, (size_t)B_ * D_ * sizeof(float), stream);

    // one-pass softmax: x2 read once -> Ft (scaled, transposed), qs
    softmax_fused_k<<<dim3(N_ / 64, B_), 256, 0, stream>>>(x2, Ft, qs);

    // bf16 W
    cvt_bf16_k<<<dim3(128), 256, 0, stream>>>(W, Wb);

    // pass 2 (SYRK): P[b,ks] = Ft-rows . Ft-cols^T over quarter-K each (128^2 tiles)
    gemm128_p2_k<<<dim3(4, 4, B_ * 4), 256, 0, stream>>>(Ft, P);

    // KQ = (P0+P1+P2+P3)/qs -> bf16
    cvt_kq_k<<<dim3(1024), 256, 0, stream>>>(P, qs, KQb);

    // pass 3: Mt[e][i] = sum_j Wb[e][j]*KQb[i][j]
    gemm64_k<<<dim3(8, 8, B_), 256, 0, stream>>>(
        Wb, KQb, Mt, 512, 0LL, (long long)512 * 512, (long long)512 * 512);

    // pass 4: out[n][e] = sum_i x[n][i]*Mt[e][i] + b[e]  (f32 A staged in-kernel)
    gemm_xf32_k<<<dim3(4, 16, B_), 256, 0, stream>>>(x, Mt, out, bias);
}